// Round 1
// baseline (536.959 us; speedup 1.0000x reference)
//
#include <hip/hip_runtime.h>
#include <math.h>

#define D 64

// ---------------------------------------------------------------------------
// Transpose W2 (64x64) -> W2t so that column j is contiguous.
__global__ __launch_bounds__(256) void k_transpose(const float* __restrict__ W2,
                                                   float* __restrict__ W2t) {
    int i = blockIdx.x * 256 + threadIdx.x;
    if (i < D * D) {
        int r = i >> 6, c = i & 63;
        W2t[c * D + r] = W2[r * D + c];
    }
}

// ---------------------------------------------------------------------------
// Segment boundaries: start[n] = lower_bound(seg_ids, n), n in [0, N].
__global__ __launch_bounds__(256) void k_bounds(const int* __restrict__ seg_ids,
                                                int* __restrict__ start, int E, int N) {
    int n = blockIdx.x * 256 + threadIdx.x;
    if (n > N) return;
    int lo = 0, hi = E;
    while (lo < hi) {
        int mid = (lo + hi) >> 1;
        if (seg_ids[mid] < n) lo = mid + 1; else hi = mid;
    }
    start[n] = lo;
}

// ---------------------------------------------------------------------------
// q[u] = u2e[u] @ W1a   (W1a = first 64 rows of W1).  Thread per row.
__global__ __launch_bounds__(256) void k_user_proj(const float* __restrict__ u2e,
                                                   const float* __restrict__ W1a,
                                                   float* __restrict__ q, int U) {
    int u = blockIdx.x * 256 + threadIdx.x;
    if (u >= U) return;
    const float4* row = (const float4*)(u2e + (size_t)u * D);
    float h[D];
#pragma unroll
    for (int j = 0; j < D; ++j) h[j] = 0.0f;
    for (int k4 = 0; k4 < 16; ++k4) {
        float4 x = row[k4];
        const float* w = W1a + (4 * k4) * D;   // 4 contiguous rows, uniform addr
#pragma unroll
        for (int j = 0; j < D; ++j)
            h[j] += x.x * w[j] + x.y * w[D + j] + x.z * w[2 * D + j] + x.w * w[3 * D + j];
    }
    float4* o = (float4*)(q + (size_t)u * D);
#pragma unroll
    for (int j4 = 0; j4 < 16; ++j4)
        o[j4] = make_float4(h[4 * j4], h[4 * j4 + 1], h[4 * j4 + 2], h[4 * j4 + 3]);
}

// p[n] = u2e[nodes[n]] @ W1b + b1   (W1b = rows 64..127 of W1).
__global__ __launch_bounds__(256) void k_node_proj(const float* __restrict__ u2e,
                                                   const int* __restrict__ nodes,
                                                   const float* __restrict__ W1b,
                                                   const float* __restrict__ b1,
                                                   float* __restrict__ p, int N) {
    int n = blockIdx.x * 256 + threadIdx.x;
    if (n >= N) return;
    int node = nodes[n];
    const float4* row = (const float4*)(u2e + (size_t)node * D);
    float h[D];
#pragma unroll
    for (int j = 0; j < D; ++j) h[j] = b1[j];
    for (int k4 = 0; k4 < 16; ++k4) {
        float4 x = row[k4];
        const float* w = W1b + (4 * k4) * D;
#pragma unroll
        for (int j = 0; j < D; ++j)
            h[j] += x.x * w[j] + x.y * w[D + j] + x.z * w[2 * D + j] + x.w * w[3 * D + j];
    }
    float4* o = (float4*)(p + (size_t)n * D);
#pragma unroll
    for (int j4 = 0; j4 < 16; ++j4)
        o[j4] = make_float4(h[4 * j4], h[4 * j4 + 1], h[4 * j4 + 2], h[4 * j4 + 3]);
}

// ---------------------------------------------------------------------------
// Per-edge: h1 = relu(q[nbr] + p[seg]); layer2 (W2t) + relu; logit = h2 . w3 + b3
__global__ __launch_bounds__(256) void k_edge_logits(const int* __restrict__ neigh_idx,
                                                     const int* __restrict__ seg_ids,
                                                     const float* __restrict__ q,
                                                     const float* __restrict__ p,
                                                     const float* __restrict__ W2t,
                                                     const float* __restrict__ b2,
                                                     const float* __restrict__ w3,
                                                     const float* __restrict__ b3,
                                                     float* __restrict__ logits, int E) {
    int e = blockIdx.x * 256 + threadIdx.x;
    if (e >= E) return;
    int nbr = neigh_idx[e];
    int seg = seg_ids[e];
    const float4* qa = (const float4*)(q + (size_t)nbr * D);
    const float4* pa = (const float4*)(p + (size_t)seg * D);
    float h1[D];
#pragma unroll
    for (int k4 = 0; k4 < 16; ++k4) {
        float4 a = qa[k4];
        float4 b = pa[k4];
        h1[4 * k4 + 0] = fmaxf(a.x + b.x, 0.0f);
        h1[4 * k4 + 1] = fmaxf(a.y + b.y, 0.0f);
        h1[4 * k4 + 2] = fmaxf(a.z + b.z, 0.0f);
        h1[4 * k4 + 3] = fmaxf(a.w + b.w, 0.0f);
    }
    float logit = b3[0];
    for (int j = 0; j < D; ++j) {                    // runtime loop; W2t col uniform
        const float4* wc = (const float4*)(W2t + j * D);
        float acc = b2[j];
#pragma unroll
        for (int k4 = 0; k4 < 16; ++k4) {
            float4 w = wc[k4];
            acc += h1[4 * k4] * w.x + h1[4 * k4 + 1] * w.y +
                   h1[4 * k4 + 2] * w.z + h1[4 * k4 + 3] * w.w;
        }
        logit += fmaxf(acc, 0.0f) * w3[j];
    }
    logits[e] = logit;
}

// ---------------------------------------------------------------------------
// Fallback (small ws): full MLP per edge (no q/p decomposition).
__global__ __launch_bounds__(256) void k_edge_logits_full(const int* __restrict__ nodes,
                                                          const int* __restrict__ neigh_idx,
                                                          const int* __restrict__ seg_ids,
                                                          const float* __restrict__ u2e,
                                                          const float* __restrict__ W1,
                                                          const float* __restrict__ b1,
                                                          const float* __restrict__ W2t,
                                                          const float* __restrict__ b2,
                                                          const float* __restrict__ w3,
                                                          const float* __restrict__ b3,
                                                          float* __restrict__ logits, int E) {
    int e = blockIdx.x * 256 + threadIdx.x;
    if (e >= E) return;
    int nbr = neigh_idx[e];
    int seg = seg_ids[e];
    int node = nodes[seg];
    const float4* arow = (const float4*)(u2e + (size_t)nbr * D);
    const float4* brow = (const float4*)(u2e + (size_t)node * D);
    float h1[D];
#pragma unroll
    for (int j = 0; j < D; ++j) h1[j] = b1[j];
    for (int k4 = 0; k4 < 16; ++k4) {
        float4 x = arow[k4];
        const float* w = W1 + (4 * k4) * D;
#pragma unroll
        for (int j = 0; j < D; ++j)
            h1[j] += x.x * w[j] + x.y * w[D + j] + x.z * w[2 * D + j] + x.w * w[3 * D + j];
    }
    for (int k4 = 0; k4 < 16; ++k4) {
        float4 x = brow[k4];
        const float* w = W1 + (D + 4 * k4) * D;
#pragma unroll
        for (int j = 0; j < D; ++j)
            h1[j] += x.x * w[j] + x.y * w[D + j] + x.z * w[2 * D + j] + x.w * w[3 * D + j];
    }
#pragma unroll
    for (int j = 0; j < D; ++j) h1[j] = fmaxf(h1[j], 0.0f);
    float logit = b3[0];
    for (int j = 0; j < D; ++j) {
        const float4* wc = (const float4*)(W2t + j * D);
        float acc = b2[j];
#pragma unroll
        for (int k4 = 0; k4 < 16; ++k4) {
            float4 w = wc[k4];
            acc += h1[4 * k4] * w.x + h1[4 * k4 + 1] * w.y +
                   h1[4 * k4 + 2] * w.z + h1[4 * k4 + 3] * w.w;
        }
        logit += fmaxf(acc, 0.0f) * w3[j];
    }
    logits[e] = logit;
}

// ---------------------------------------------------------------------------
// Wave per node: segment softmax (max, sum) + attention-weighted aggregation.
__global__ __launch_bounds__(256) void k_agg(const int* __restrict__ nodes,
                                             const int* __restrict__ neigh_idx,
                                             const float* __restrict__ u2e,
                                             const float* __restrict__ logits,
                                             const int* __restrict__ start,
                                             float* __restrict__ out, int N) {
    int wave = (blockIdx.x * 256 + threadIdx.x) >> 6;
    int lane = threadIdx.x & 63;
    if (wave >= N) return;
    int n = wave;
    int s = start[n];
    int t = start[n + 1];
    if (s == t) {  // no neighbors: fall back to own embedding
        int node = nodes[n];
        out[(size_t)n * D + lane] = u2e[(size_t)node * D + lane];
        return;
    }
    float m = -INFINITY;
    for (int i = s + lane; i < t; i += 64) m = fmaxf(m, logits[i]);
#pragma unroll
    for (int off = 32; off >= 1; off >>= 1) m = fmaxf(m, __shfl_xor(m, off, 64));
    float ssum = 0.0f;
    for (int i = s + lane; i < t; i += 64) ssum += __expf(logits[i] - m);
#pragma unroll
    for (int off = 32; off >= 1; off >>= 1) ssum += __shfl_xor(ssum, off, 64);
    float inv = 1.0f / ssum;
    float acc = 0.0f;
    for (int i = s; i < t; ++i) {
        float att = __expf(logits[i] - m) * inv;  // uniform across wave
        int nbr = neigh_idx[i];                   // uniform
        acc += att * u2e[(size_t)nbr * D + lane]; // coalesced 256B row load
    }
    out[(size_t)n * D + lane] = acc;
}

// ---------------------------------------------------------------------------
extern "C" void kernel_launch(void* const* d_in, const int* in_sizes, int n_in,
                              void* d_out, int out_size, void* d_ws, size_t ws_size,
                              hipStream_t stream) {
    const int* nodes = (const int*)d_in[0];
    const int* neigh_idx = (const int*)d_in[1];
    const int* seg_ids = (const int*)d_in[2];
    const float* u2e = (const float*)d_in[3];
    const float* W1 = (const float*)d_in[4];
    const float* b1 = (const float*)d_in[5];
    const float* W2 = (const float*)d_in[6];
    const float* b2 = (const float*)d_in[7];
    const float* w3 = (const float*)d_in[8];
    const float* b3 = (const float*)d_in[9];
    float* out = (float*)d_out;

    int N = in_sizes[0];
    int E = in_sizes[1];
    int U = in_sizes[3] / D;

    char* ws = (char*)d_ws;
    size_t off = 0;
    auto alloc = [&](size_t bytes) {
        void* ptr = ws + off;
        off = (off + bytes + 255) & ~(size_t)255;
        return ptr;
    };
    float* logits = (float*)alloc((size_t)E * 4);
    int* start = (int*)alloc((size_t)(N + 1) * 4);
    float* W2t = (float*)alloc((size_t)D * D * 4);
    size_t base = off;
    float* q = (float*)alloc((size_t)U * D * 4);
    float* p = (float*)alloc((size_t)N * D * 4);
    bool fast = (off <= ws_size);

    k_transpose<<<(D * D + 255) / 256, 256, 0, stream>>>(W2, W2t);
    k_bounds<<<(N + 1 + 255) / 256, 256, 0, stream>>>(seg_ids, start, E, N);

    if (fast) {
        k_user_proj<<<(U + 255) / 256, 256, 0, stream>>>(u2e, W1, q, U);
        k_node_proj<<<(N + 255) / 256, 256, 0, stream>>>(u2e, nodes, W1 + (size_t)D * D, b1, p, N);
        k_edge_logits<<<(E + 255) / 256, 256, 0, stream>>>(neigh_idx, seg_ids, q, p, W2t,
                                                           b2, w3, b3, logits, E);
    } else {
        (void)base;
        k_edge_logits_full<<<(E + 255) / 256, 256, 0, stream>>>(nodes, neigh_idx, seg_ids, u2e,
                                                                W1, b1, W2t, b2, w3, b3, logits, E);
    }
    k_agg<<<(N + 3) / 4, 256, 0, stream>>>(nodes, neigh_idx, u2e, logits, start, out, N);
}

// Round 2
// 274.985 us; speedup vs baseline: 1.9527x; 1.9527x over previous
//
#include <hip/hip_runtime.h>
#include <math.h>

#define D 64

typedef __attribute__((ext_vector_type(8))) short bf16x8;
typedef __attribute__((ext_vector_type(8))) short s8v;
typedef __attribute__((ext_vector_type(4))) float f32x4;

__device__ inline unsigned short f2bf(float f) {
    unsigned x = __float_as_uint(f);
    unsigned r = (x + 0x7FFFu + ((x >> 16) & 1u)) >> 16;   // RNE
    return (unsigned short)r;
}
__device__ inline float bf2f(unsigned short h) {
    return __uint_as_float(((unsigned)h) << 16);
}

// ---------------------------------------------------------------------------
// Transposes: W1at[c][r]=W1[r][c] (rows 0..63), W1bt[c][r]=W1[64+r][c],
// W2t[c][r]=W2[r][c].  3 * 4096 elements.
__global__ __launch_bounds__(256) void k_transpose_all(const float* __restrict__ W1,
                                                       const float* __restrict__ W2,
                                                       float* __restrict__ W1at,
                                                       float* __restrict__ W1bt,
                                                       float* __restrict__ W2t) {
    int i = blockIdx.x * 256 + threadIdx.x;
    if (i >= 3 * D * D) return;
    int mat = i / (D * D), j = i % (D * D);
    int r = j >> 6, c = j & 63;
    if (mat == 0)      W1at[c * D + r] = W1[r * D + c];
    else if (mat == 1) W1bt[c * D + r] = W1[(D + r) * D + c];
    else               W2t[c * D + r] = W2[r * D + c];
}

// ---------------------------------------------------------------------------
// Segment boundaries: start[n] = lower_bound(seg_ids, n).
__global__ __launch_bounds__(256) void k_bounds(const int* __restrict__ seg_ids,
                                                int* __restrict__ start, int E, int N) {
    int n = blockIdx.x * 256 + threadIdx.x;
    if (n > N) return;
    int lo = 0, hi = E;
    while (lo < hi) {
        int mid = (lo + hi) >> 1;
        if (seg_ids[mid] < n) lo = mid + 1; else hi = mid;
    }
    start[n] = lo;
}

// ---------------------------------------------------------------------------
// MFMA row-projection: outp[r] = (idx ? u2e[idx[r]] : u2e[r]) @ W + bias,
// stored bf16 row-major [R][64].  Wt is W transposed (col-major cols).
// 16 rows per wave per group; grid-stride over groups.
__global__ __launch_bounds__(256) void k_proj_mfma(const float* __restrict__ u2e,
                                                   const int* __restrict__ idx,
                                                   const float* __restrict__ Wt,
                                                   const float* __restrict__ bias,
                                                   unsigned short* __restrict__ outp,
                                                   int R) {
    int lane = threadIdx.x & 63;
    int m = lane & 15, quad = lane >> 4;

    // B fragments: B[k=quad*8+j + 32*kh][n=m+16*t]  from Wt[n*64+k]
    bf16x8 Bf[2][4];
    float bv[4];
#pragma unroll
    for (int t = 0; t < 4; ++t) {
        int n = m + 16 * t;
        bv[t] = bias ? bias[n] : 0.0f;
#pragma unroll
        for (int kh = 0; kh < 2; ++kh) {
            const float* col = Wt + n * D + kh * 32 + quad * 8;
#pragma unroll
            for (int j = 0; j < 8; ++j) Bf[kh][t][j] = (short)f2bf(col[j]);
        }
    }

    int ngroups = (R + 15) / 16;
    int wave = (blockIdx.x * blockDim.x + threadIdx.x) >> 6;
    int nwaves = (gridDim.x * blockDim.x) >> 6;
    for (int g = wave; g < ngroups; g += nwaves) {
        int r_ = g * 16 + m;
        int rs = r_ < R ? r_ : R - 1;
        int src = idx ? idx[rs] : rs;
        const float4* arow = (const float4*)(u2e + (size_t)src * D);
        bf16x8 A0, A1;
        {
            float4 x0 = arow[quad * 2], x1 = arow[quad * 2 + 1];
            float4 y0 = arow[8 + quad * 2], y1 = arow[8 + quad * 2 + 1];
            A0[0] = (short)f2bf(x0.x); A0[1] = (short)f2bf(x0.y);
            A0[2] = (short)f2bf(x0.z); A0[3] = (short)f2bf(x0.w);
            A0[4] = (short)f2bf(x1.x); A0[5] = (short)f2bf(x1.y);
            A0[6] = (short)f2bf(x1.z); A0[7] = (short)f2bf(x1.w);
            A1[0] = (short)f2bf(y0.x); A1[1] = (short)f2bf(y0.y);
            A1[2] = (short)f2bf(y0.z); A1[3] = (short)f2bf(y0.w);
            A1[4] = (short)f2bf(y1.x); A1[5] = (short)f2bf(y1.y);
            A1[6] = (short)f2bf(y1.z); A1[7] = (short)f2bf(y1.w);
        }
        f32x4 C[4] = {{0,0,0,0},{0,0,0,0},{0,0,0,0},{0,0,0,0}};
#pragma unroll
        for (int t = 0; t < 4; ++t) {
            C[t] = __builtin_amdgcn_mfma_f32_16x16x32_bf16(A0, Bf[0][t], C[t], 0, 0, 0);
            C[t] = __builtin_amdgcn_mfma_f32_16x16x32_bf16(A1, Bf[1][t], C[t], 0, 0, 0);
        }
        // store: row = g*16 + quad*4 + r, col = m + 16*t
#pragma unroll
        for (int r = 0; r < 4; ++r) {
            int row = g * 16 + quad * 4 + r;
            if (row < R) {
#pragma unroll
                for (int t = 0; t < 4; ++t)
                    outp[(size_t)row * D + m + 16 * t] = f2bf(C[t][r] + bv[t]);
            }
        }
    }
}

// ---------------------------------------------------------------------------
// Edge logits via MFMA: h1 = relu(q[nbr]+p[seg]) (bf16), h2 = relu(h1@W2+b2),
// logit = h2.w3 + b3.  16 edges per wave-iteration.
__global__ __launch_bounds__(256) void k_edge_logits_mfma(const int* __restrict__ neigh_idx,
                                                          const int* __restrict__ seg_ids,
                                                          const unsigned short* __restrict__ q,
                                                          const unsigned short* __restrict__ p,
                                                          const float* __restrict__ W2t,
                                                          const float* __restrict__ b2,
                                                          const float* __restrict__ w3,
                                                          const float* __restrict__ b3,
                                                          float* __restrict__ logits, int E) {
    int lane = threadIdx.x & 63;
    int m = lane & 15, quad = lane >> 4;

    bf16x8 Bf[2][4];
    float b2v[4], w3v[4];
#pragma unroll
    for (int t = 0; t < 4; ++t) {
        int n = m + 16 * t;
        b2v[t] = b2[n];
        w3v[t] = w3[n];
#pragma unroll
        for (int kh = 0; kh < 2; ++kh) {
            const float* col = W2t + n * D + kh * 32 + quad * 8;
#pragma unroll
            for (int j = 0; j < 8; ++j) Bf[kh][t][j] = (short)f2bf(col[j]);
        }
    }
    float b3v = b3[0];

    int ngroups = (E + 15) / 16;
    int wave = (blockIdx.x * blockDim.x + threadIdx.x) >> 6;
    int nwaves = (gridDim.x * blockDim.x) >> 6;
    for (int g = wave; g < ngroups; g += nwaves) {
        int e = g * 16 + m;
        int es = e < E ? e : E - 1;
        int nbr = neigh_idx[es];
        int seg = seg_ids[es];
        const s8v* qrow = (const s8v*)(q + (size_t)nbr * D);
        const s8v* prow = (const s8v*)(p + (size_t)seg * D);
        s8v qa0 = qrow[quad], qa1 = qrow[quad + 4];
        s8v pa0 = prow[quad], pa1 = prow[quad + 4];
        bf16x8 A0, A1;
#pragma unroll
        for (int j = 0; j < 8; ++j) {
            float s0 = fmaxf(bf2f((unsigned short)qa0[j]) + bf2f((unsigned short)pa0[j]), 0.0f);
            float s1 = fmaxf(bf2f((unsigned short)qa1[j]) + bf2f((unsigned short)pa1[j]), 0.0f);
            A0[j] = (short)f2bf(s0);
            A1[j] = (short)f2bf(s1);
        }
        f32x4 C[4] = {{0,0,0,0},{0,0,0,0},{0,0,0,0},{0,0,0,0}};
#pragma unroll
        for (int t = 0; t < 4; ++t) {
            C[t] = __builtin_amdgcn_mfma_f32_16x16x32_bf16(A0, Bf[0][t], C[t], 0, 0, 0);
            C[t] = __builtin_amdgcn_mfma_f32_16x16x32_bf16(A1, Bf[1][t], C[t], 0, 0, 0);
        }
        // epilogue: logit[row] = sum_n relu(C[row][n]+b2[n])*w3[n] + b3
        float part[4];
#pragma unroll
        for (int r = 0; r < 4; ++r) {
            float s = 0.0f;
#pragma unroll
            for (int t = 0; t < 4; ++t)
                s += fmaxf(C[t][r] + b2v[t], 0.0f) * w3v[t];
            part[r] = s;
        }
#pragma unroll
        for (int off = 1; off <= 8; off <<= 1) {
#pragma unroll
            for (int r = 0; r < 4; ++r)
                part[r] += __shfl_xor(part[r], off, 64);
        }
        if (m == 0) {
            int e0 = g * 16 + quad * 4;   // rows quad*4 + r
            if (e0 + 3 < E) {
                float4 v = make_float4(part[0] + b3v, part[1] + b3v,
                                       part[2] + b3v, part[3] + b3v);
                *(float4*)(logits + e0) = v;
            } else {
#pragma unroll
                for (int r = 0; r < 4; ++r)
                    if (e0 + r < E) logits[e0 + r] = part[r] + b3v;
            }
        }
    }
}

// ---------------------------------------------------------------------------
// Wave per node: softmax stats (lane-parallel), att written in place, then
// aggregation with 4 neighbors in flight (quad-per-neighbor, float4 per lane).
__global__ __launch_bounds__(256) void k_agg(const int* __restrict__ nodes,
                                             const int* __restrict__ neigh_idx,
                                             const float* __restrict__ u2e,
                                             float* __restrict__ att,   // in: logits
                                             const int* __restrict__ start,
                                             float* __restrict__ out, int N) {
    int n = __builtin_amdgcn_readfirstlane(blockIdx.x * 4 + ((int)threadIdx.x >> 6));
    int lane = threadIdx.x & 63;
    if (n >= N) return;
    int s = start[n];
    int t = start[n + 1];
    if (s == t) {  // no neighbors: own embedding
        int node = nodes[n];
        out[(size_t)n * D + lane] = u2e[(size_t)node * D + lane];
        return;
    }
    // max
    float mx = -INFINITY;
    for (int i = s + lane; i < t; i += 64) mx = fmaxf(mx, att[i]);
#pragma unroll
    for (int off = 32; off >= 1; off >>= 1) mx = fmaxf(mx, __shfl_xor(mx, off, 64));
    // sum of exp
    float ssum = 0.0f;
    for (int i = s + lane; i < t; i += 64) ssum += __expf(att[i] - mx);
#pragma unroll
    for (int off = 32; off >= 1; off >>= 1) ssum += __shfl_xor(ssum, off, 64);
    float inv = 1.0f / ssum;
    // write normalized attention in place (lane-parallel)
    for (int i = s + lane; i < t; i += 64) att[i] = __expf(att[i] - mx) * inv;
    // aggregate: quad handles neighbor i+quad; lane covers cols 4m..4m+3
    int m = lane & 15, quad = lane >> 4;
    float4 acc = make_float4(0.f, 0.f, 0.f, 0.f);
    for (int i = s; i < t; i += 4) {
        int ii = i + quad;
        bool v = ii < t;
        float a = v ? att[ii] : 0.0f;
        int nbr = v ? neigh_idx[ii] : 0;
        float4 row = ((const float4*)(u2e + (size_t)nbr * D))[m];
        acc.x += a * row.x; acc.y += a * row.y;
        acc.z += a * row.z; acc.w += a * row.w;
    }
#pragma unroll
    for (int off = 16; off <= 32; off <<= 1) {
        acc.x += __shfl_xor(acc.x, off, 64);
        acc.y += __shfl_xor(acc.y, off, 64);
        acc.z += __shfl_xor(acc.z, off, 64);
        acc.w += __shfl_xor(acc.w, off, 64);
    }
    if (quad == 0) ((float4*)(out + (size_t)n * D))[m] = acc;
}

// ---------------------------------------------------------------------------
extern "C" void kernel_launch(void* const* d_in, const int* in_sizes, int n_in,
                              void* d_out, int out_size, void* d_ws, size_t ws_size,
                              hipStream_t stream) {
    const int* nodes = (const int*)d_in[0];
    const int* neigh_idx = (const int*)d_in[1];
    const int* seg_ids = (const int*)d_in[2];
    const float* u2e = (const float*)d_in[3];
    const float* W1 = (const float*)d_in[4];
    const float* b1 = (const float*)d_in[5];
    const float* W2 = (const float*)d_in[6];
    const float* b2 = (const float*)d_in[7];
    const float* w3 = (const float*)d_in[8];
    const float* b3 = (const float*)d_in[9];
    float* out = (float*)d_out;

    int N = in_sizes[0];
    int E = in_sizes[1];
    int U = in_sizes[3] / D;

    char* ws = (char*)d_ws;
    size_t off = 0;
    auto alloc = [&](size_t bytes) {
        void* ptr = ws + off;
        off = (off + bytes + 255) & ~(size_t)255;
        return ptr;
    };
    float* logits = (float*)alloc((size_t)E * 4);
    int* start = (int*)alloc((size_t)(N + 1) * 4);
    float* W1at = (float*)alloc((size_t)D * D * 4);
    float* W1bt = (float*)alloc((size_t)D * D * 4);
    float* W2t = (float*)alloc((size_t)D * D * 4);
    unsigned short* q = (unsigned short*)alloc((size_t)U * D * 2);
    unsigned short* p = (unsigned short*)alloc((size_t)N * D * 2);
    (void)ws_size;

    k_transpose_all<<<(3 * D * D + 255) / 256, 256, 0, stream>>>(W1, W2, W1at, W1bt, W2t);
    k_bounds<<<(N + 1 + 255) / 256, 256, 0, stream>>>(seg_ids, start, E, N);
    k_proj_mfma<<<1024, 256, 0, stream>>>(u2e, nullptr, W1at, nullptr, q, U);
    k_proj_mfma<<<256, 256, 0, stream>>>(u2e, nodes, W1bt, b1, p, N);
    k_edge_logits_mfma<<<2048, 256, 0, stream>>>(neigh_idx, seg_ids, q, p, W2t,
                                                 b2, w3, b3, logits, E);
    k_agg<<<(N + 3) / 4, 256, 0, stream>>>(nodes, neigh_idx, u2e, logits, start, out, N);
}

// Round 3
// 246.302 us; speedup vs baseline: 2.1801x; 1.1165x over previous
//
#include <hip/hip_runtime.h>
#include <math.h>

#define D 64

typedef __attribute__((ext_vector_type(8))) short bf16x8;
typedef __attribute__((ext_vector_type(8))) short s8v;
typedef __attribute__((ext_vector_type(4))) float f32x4;

__device__ inline unsigned short f2bf(float f) {
    unsigned x = __float_as_uint(f);
    unsigned r = (x + 0x7FFFu + ((x >> 16) & 1u)) >> 16;   // RNE
    return (unsigned short)r;
}
__device__ inline float bf2f(unsigned short h) {
    return __uint_as_float(((unsigned)h) << 16);
}

// ---------------------------------------------------------------------------
// Transposes: W1at[c][r]=W1[r][c] (rows 0..63), W1bt[c][r]=W1[64+r][c],
// W2t[c][r]=W2[r][c].
__global__ __launch_bounds__(256) void k_transpose_all(const float* __restrict__ W1,
                                                       const float* __restrict__ W2,
                                                       float* __restrict__ W1at,
                                                       float* __restrict__ W1bt,
                                                       float* __restrict__ W2t) {
    int i = blockIdx.x * 256 + threadIdx.x;
    if (i >= 3 * D * D) return;
    int mat = i / (D * D), j = i % (D * D);
    int r = j >> 6, c = j & 63;
    if (mat == 0)      W1at[c * D + r] = W1[r * D + c];
    else if (mat == 1) W1bt[c * D + r] = W1[(D + r) * D + c];
    else               W2t[c * D + r] = W2[r * D + c];
}

// ---------------------------------------------------------------------------
__global__ __launch_bounds__(256) void k_bounds(const int* __restrict__ seg_ids,
                                                int* __restrict__ start, int E, int N) {
    int n = blockIdx.x * 256 + threadIdx.x;
    if (n > N) return;
    int lo = 0, hi = E;
    while (lo < hi) {
        int mid = (lo + hi) >> 1;
        if (seg_ids[mid] < n) lo = mid + 1; else hi = mid;
    }
    start[n] = lo;
}

// ---------------------------------------------------------------------------
// MFMA row-projection: outp[r] = (idx ? u2e[idx[r]] : u2e[r]) @ W + bias, bf16.
// When u2e_bf != nullptr (idx==nullptr pass), also stores the bf16 A-rows as a
// bf16 copy of u2e (free: fragments already converted in registers).
__global__ __launch_bounds__(256) void k_proj_mfma(const float* __restrict__ u2e,
                                                   const int* __restrict__ idx,
                                                   const float* __restrict__ Wt,
                                                   const float* __restrict__ bias,
                                                   unsigned short* __restrict__ outp,
                                                   unsigned short* __restrict__ u2e_bf,
                                                   int R) {
    int lane = threadIdx.x & 63;
    int m = lane & 15, quad = lane >> 4;

    bf16x8 Bf[2][4];
    float bv[4];
#pragma unroll
    for (int t = 0; t < 4; ++t) {
        int n = m + 16 * t;
        bv[t] = bias ? bias[n] : 0.0f;
#pragma unroll
        for (int kh = 0; kh < 2; ++kh) {
            const float* col = Wt + n * D + kh * 32 + quad * 8;
#pragma unroll
            for (int j = 0; j < 8; ++j) Bf[kh][t][j] = (short)f2bf(col[j]);
        }
    }

    int ngroups = (R + 15) / 16;
    int wave = (blockIdx.x * blockDim.x + threadIdx.x) >> 6;
    int nwaves = (gridDim.x * blockDim.x) >> 6;
    for (int g = wave; g < ngroups; g += nwaves) {
        int r_ = g * 16 + m;
        int rs = r_ < R ? r_ : R - 1;
        int src = idx ? idx[rs] : rs;
        const float4* arow = (const float4*)(u2e + (size_t)src * D);
        bf16x8 A0, A1;
        {
            float4 x0 = arow[quad * 2], x1 = arow[quad * 2 + 1];
            float4 y0 = arow[8 + quad * 2], y1 = arow[8 + quad * 2 + 1];
            A0[0] = (short)f2bf(x0.x); A0[1] = (short)f2bf(x0.y);
            A0[2] = (short)f2bf(x0.z); A0[3] = (short)f2bf(x0.w);
            A0[4] = (short)f2bf(x1.x); A0[5] = (short)f2bf(x1.y);
            A0[6] = (short)f2bf(x1.z); A0[7] = (short)f2bf(x1.w);
            A1[0] = (short)f2bf(y0.x); A1[1] = (short)f2bf(y0.y);
            A1[2] = (short)f2bf(y0.z); A1[3] = (short)f2bf(y0.w);
            A1[4] = (short)f2bf(y1.x); A1[5] = (short)f2bf(y1.y);
            A1[6] = (short)f2bf(y1.z); A1[7] = (short)f2bf(y1.w);
        }
        if (u2e_bf && r_ < R) {   // bf16 copy of u2e row r_ (A layout covers it)
            *(s8v*)(u2e_bf + (size_t)r_ * D + quad * 8) = A0;
            *(s8v*)(u2e_bf + (size_t)r_ * D + 32 + quad * 8) = A1;
        }
        f32x4 C[4] = {{0,0,0,0},{0,0,0,0},{0,0,0,0},{0,0,0,0}};
#pragma unroll
        for (int t = 0; t < 4; ++t) {
            C[t] = __builtin_amdgcn_mfma_f32_16x16x32_bf16(A0, Bf[0][t], C[t], 0, 0, 0);
            C[t] = __builtin_amdgcn_mfma_f32_16x16x32_bf16(A1, Bf[1][t], C[t], 0, 0, 0);
        }
#pragma unroll
        for (int r = 0; r < 4; ++r) {
            int row = g * 16 + quad * 4 + r;
            if (row < R) {
#pragma unroll
                for (int t = 0; t < 4; ++t)
                    outp[(size_t)row * D + m + 16 * t] = f2bf(C[t][r] + bv[t]);
            }
        }
    }
}

// ---------------------------------------------------------------------------
// Edge logits via MFMA, 32 edges per wave-iteration (two A-sets share B-frags).
__global__ __launch_bounds__(256) void k_edge_logits_mfma(const int* __restrict__ neigh_idx,
                                                          const int* __restrict__ seg_ids,
                                                          const unsigned short* __restrict__ q,
                                                          const unsigned short* __restrict__ p,
                                                          const float* __restrict__ W2t,
                                                          const float* __restrict__ b2,
                                                          const float* __restrict__ w3,
                                                          const float* __restrict__ b3,
                                                          float* __restrict__ logits, int E) {
    int lane = threadIdx.x & 63;
    int m = lane & 15, quad = lane >> 4;

    bf16x8 Bf[2][4];
    float b2v[4], w3v[4];
#pragma unroll
    for (int t = 0; t < 4; ++t) {
        int n = m + 16 * t;
        b2v[t] = b2[n];
        w3v[t] = w3[n];
#pragma unroll
        for (int kh = 0; kh < 2; ++kh) {
            const float* col = W2t + n * D + kh * 32 + quad * 8;
#pragma unroll
            for (int j = 0; j < 8; ++j) Bf[kh][t][j] = (short)f2bf(col[j]);
        }
    }
    float b3v = b3[0];

    int ngroups = (E + 31) / 32;
    int wave = (blockIdx.x * blockDim.x + threadIdx.x) >> 6;
    int nwaves = (gridDim.x * blockDim.x) >> 6;
    for (int g = wave; g < ngroups; g += nwaves) {
        int ea = g * 32 + m, eb = ea + 16;
        int eas = ea < E ? ea : E - 1;
        int ebs = eb < E ? eb : E - 1;
        int nbra = neigh_idx[eas], sega = seg_ids[eas];
        int nbrb = neigh_idx[ebs], segb = seg_ids[ebs];
        const s8v* qra = (const s8v*)(q + (size_t)nbra * D);
        const s8v* pra = (const s8v*)(p + (size_t)sega * D);
        const s8v* qrb = (const s8v*)(q + (size_t)nbrb * D);
        const s8v* prb = (const s8v*)(p + (size_t)segb * D);
        s8v qa0 = qra[quad], qa1 = qra[quad + 4];
        s8v pa0 = pra[quad], pa1 = pra[quad + 4];
        s8v qb0 = qrb[quad], qb1 = qrb[quad + 4];
        s8v pb0 = prb[quad], pb1 = prb[quad + 4];
        bf16x8 Aa0, Aa1, Ab0, Ab1;
#pragma unroll
        for (int j = 0; j < 8; ++j) {
            Aa0[j] = (short)f2bf(fmaxf(bf2f((unsigned short)qa0[j]) + bf2f((unsigned short)pa0[j]), 0.0f));
            Aa1[j] = (short)f2bf(fmaxf(bf2f((unsigned short)qa1[j]) + bf2f((unsigned short)pa1[j]), 0.0f));
            Ab0[j] = (short)f2bf(fmaxf(bf2f((unsigned short)qb0[j]) + bf2f((unsigned short)pb0[j]), 0.0f));
            Ab1[j] = (short)f2bf(fmaxf(bf2f((unsigned short)qb1[j]) + bf2f((unsigned short)pb1[j]), 0.0f));
        }
        f32x4 Ca[4] = {{0,0,0,0},{0,0,0,0},{0,0,0,0},{0,0,0,0}};
        f32x4 Cb[4] = {{0,0,0,0},{0,0,0,0},{0,0,0,0},{0,0,0,0}};
#pragma unroll
        for (int t = 0; t < 4; ++t) {
            Ca[t] = __builtin_amdgcn_mfma_f32_16x16x32_bf16(Aa0, Bf[0][t], Ca[t], 0, 0, 0);
            Ca[t] = __builtin_amdgcn_mfma_f32_16x16x32_bf16(Aa1, Bf[1][t], Ca[t], 0, 0, 0);
            Cb[t] = __builtin_amdgcn_mfma_f32_16x16x32_bf16(Ab0, Bf[0][t], Cb[t], 0, 0, 0);
            Cb[t] = __builtin_amdgcn_mfma_f32_16x16x32_bf16(Ab1, Bf[1][t], Cb[t], 0, 0, 0);
        }
        float pa[4], pb[4];
#pragma unroll
        for (int r = 0; r < 4; ++r) {
            float sa = 0.0f, sb = 0.0f;
#pragma unroll
            for (int t = 0; t < 4; ++t) {
                sa += fmaxf(Ca[t][r] + b2v[t], 0.0f) * w3v[t];
                sb += fmaxf(Cb[t][r] + b2v[t], 0.0f) * w3v[t];
            }
            pa[r] = sa; pb[r] = sb;
        }
#pragma unroll
        for (int off = 1; off <= 8; off <<= 1) {
#pragma unroll
            for (int r = 0; r < 4; ++r) {
                pa[r] += __shfl_xor(pa[r], off, 64);
                pb[r] += __shfl_xor(pb[r], off, 64);
            }
        }
        if (m == 0) {
            int e0 = g * 32 + quad * 4;
            if (e0 + 3 < E)
                *(float4*)(logits + e0) = make_float4(pa[0] + b3v, pa[1] + b3v, pa[2] + b3v, pa[3] + b3v);
            else
#pragma unroll
                for (int r = 0; r < 4; ++r)
                    if (e0 + r < E) logits[e0 + r] = pa[r] + b3v;
            int e1 = e0 + 16;
            if (e1 + 3 < E)
                *(float4*)(logits + e1) = make_float4(pb[0] + b3v, pb[1] + b3v, pb[2] + b3v, pb[3] + b3v);
            else
#pragma unroll
                for (int r = 0; r < 4; ++r)
                    if (e1 + r < E) logits[e1 + r] = pb[r] + b3v;
        }
    }
}

// ---------------------------------------------------------------------------
// Wave per node: softmax stats, then aggregation from bf16 u2e copy.
// 8 lane-groups x 2-deep unroll = 16 neighbor rows in flight per wave.
__global__ __launch_bounds__(256) void k_agg(const int* __restrict__ nodes,
                                             const int* __restrict__ neigh_idx,
                                             const float* __restrict__ u2e,
                                             const unsigned short* __restrict__ u2e_bf,
                                             const float* __restrict__ logits,
                                             const int* __restrict__ start,
                                             float* __restrict__ out, int N) {
    int n = blockIdx.x * 4 + ((int)threadIdx.x >> 6);
    int lane = threadIdx.x & 63;
    if (n >= N) return;
    int s = start[n];
    int t = start[n + 1];
    if (s == t) {  // no neighbors: own embedding (fp32, exact)
        int node = nodes[n];
        out[(size_t)n * D + lane] = u2e[(size_t)node * D + lane];
        return;
    }
    float mx = -INFINITY;
    for (int i = s + lane; i < t; i += 64) mx = fmaxf(mx, logits[i]);
#pragma unroll
    for (int off = 32; off >= 1; off >>= 1) mx = fmaxf(mx, __shfl_xor(mx, off, 64));
    float ssum = 0.0f;
    for (int i = s + lane; i < t; i += 64) ssum += __expf(logits[i] - mx);
#pragma unroll
    for (int off = 32; off >= 1; off >>= 1) ssum += __shfl_xor(ssum, off, 64);
    float inv = 1.0f / ssum;

    int grp = lane >> 3, sub = lane & 7;   // 8 groups of 8 lanes
    float acc[8];
#pragma unroll
    for (int j = 0; j < 8; ++j) acc[j] = 0.0f;
    for (int i = s; i < t; i += 16) {
        int ii0 = i + grp, ii1 = i + 8 + grp;
        bool v0 = ii0 < t, v1 = ii1 < t;
        int is0 = v0 ? ii0 : s, is1 = v1 ? ii1 : s;
        float lg0 = logits[is0];
        float lg1 = logits[is1];
        int nb0 = neigh_idx[is0];
        int nb1 = neigh_idx[is1];
        s8v r0 = *(const s8v*)(u2e_bf + (size_t)nb0 * D + sub * 8);
        s8v r1 = *(const s8v*)(u2e_bf + (size_t)nb1 * D + sub * 8);
        float a0 = v0 ? __expf(lg0 - mx) * inv : 0.0f;
        float a1 = v1 ? __expf(lg1 - mx) * inv : 0.0f;
#pragma unroll
        for (int j = 0; j < 8; ++j) {
            acc[j] += a0 * bf2f((unsigned short)r0[j]);
            acc[j] += a1 * bf2f((unsigned short)r1[j]);
        }
    }
#pragma unroll
    for (int off = 8; off <= 32; off <<= 1) {
#pragma unroll
        for (int j = 0; j < 8; ++j) acc[j] += __shfl_xor(acc[j], off, 64);
    }
    if (grp == 0) {
        float* o = out + (size_t)n * D + sub * 8;
        *(float4*)o = make_float4(acc[0], acc[1], acc[2], acc[3]);
        *(float4*)(o + 4) = make_float4(acc[4], acc[5], acc[6], acc[7]);
    }
}

// ---------------------------------------------------------------------------
extern "C" void kernel_launch(void* const* d_in, const int* in_sizes, int n_in,
                              void* d_out, int out_size, void* d_ws, size_t ws_size,
                              hipStream_t stream) {
    const int* nodes = (const int*)d_in[0];
    const int* neigh_idx = (const int*)d_in[1];
    const int* seg_ids = (const int*)d_in[2];
    const float* u2e = (const float*)d_in[3];
    const float* W1 = (const float*)d_in[4];
    const float* b1 = (const float*)d_in[5];
    const float* W2 = (const float*)d_in[6];
    const float* b2 = (const float*)d_in[7];
    const float* w3 = (const float*)d_in[8];
    const float* b3 = (const float*)d_in[9];
    float* out = (float*)d_out;

    int N = in_sizes[0];
    int E = in_sizes[1];
    int U = in_sizes[3] / D;

    char* ws = (char*)d_ws;
    size_t off = 0;
    auto alloc = [&](size_t bytes) {
        void* ptr = ws + off;
        off = (off + bytes + 255) & ~(size_t)255;
        return ptr;
    };
    float* logits = (float*)alloc((size_t)E * 4);
    int* start = (int*)alloc((size_t)(N + 1) * 4);
    float* W1at = (float*)alloc((size_t)D * D * 4);
    float* W1bt = (float*)alloc((size_t)D * D * 4);
    float* W2t = (float*)alloc((size_t)D * D * 4);
    unsigned short* q = (unsigned short*)alloc((size_t)U * D * 2);
    unsigned short* p = (unsigned short*)alloc((size_t)N * D * 2);
    unsigned short* u2e_bf = (unsigned short*)alloc((size_t)U * D * 2);
    (void)ws_size;

    k_transpose_all<<<(3 * D * D + 255) / 256, 256, 0, stream>>>(W1, W2, W1at, W1bt, W2t);
    k_bounds<<<(N + 1 + 255) / 256, 256, 0, stream>>>(seg_ids, start, E, N);
    k_proj_mfma<<<1024, 256, 0, stream>>>(u2e, nullptr, W1at, nullptr, q, u2e_bf, U);
    k_proj_mfma<<<256, 256, 0, stream>>>(u2e, nodes, W1bt, b1, p, nullptr, N);
    k_edge_logits_mfma<<<2048, 256, 0, stream>>>(neigh_idx, seg_ids, q, p, W2t,
                                                 b2, w3, b3, logits, E);
    k_agg<<<(N + 3) / 4, 256, 0, stream>>>(nodes, neigh_idx, u2e, u2e_bf, logits, start, out, N);
}